// Round 1
// baseline (14210.068 us; speedup 1.0000x reference)
//
#include <hip/hip_runtime.h>
#include <cstdint>
#include <cstddef>

#define NX 36
#define NU 12
#define NSC 48
#define NLS 10
#define REG_EPS 1e-6f

// ---------------------------------------------------------------------------
// Backward Riccati recursion. One block per batch element, 256 threads.
// Per step: FV = F^T V (4x4 reg tiles), Q = FV*F + diag, q, a 12x12 SPD solve
// with 37 RHS done in wave-0 registers via shuffles, Vn = Qxx + Qxu K
// (symmetrized next iteration), K/kv written to global workspace.
// ---------------------------------------------------------------------------
__global__ __launch_bounds__(256, 4) void lqr_bwd(
    const float* __restrict__ Cdiag, const float* __restrict__ cvec,
    const float* __restrict__ Fmat, const float* __restrict__ fvec,
    float* __restrict__ Kg, float* __restrict__ kvg, int T)
{
    const int b = blockIdx.x;
    const int tid = threadIdx.x;

    __shared__ __align__(16) float sV[NX * NX];
    __shared__ float sv[NX];
    __shared__ __align__(16) float sF[NX * NSC];
    __shared__ __align__(16) float sFV[NSC * NX];   // FV; reused for unsym Vn
    __shared__ __align__(16) float sQ[NSC * NSC];
    __shared__ float sq[NSC];
    __shared__ float sCd[NSC];
    __shared__ float sc[NSC];
    __shared__ float sf[NX];
    __shared__ __align__(16) float sK[NU * NX];
    __shared__ float sKv[NU];

    const size_t bT = (size_t)b * (size_t)T;

    for (int i = tid; i < NX * NX; i += 256) sV[i] = 0.f;
    if (tid < NX) sv[tid] = 0.f;

    for (int t = T - 1; t >= 0; --t) {
        // ---- phase A: stage inputs for step t; symmetrize previous Vn ----
        {
            const float4* Fg = (const float4*)(Fmat + (bT + t) * (size_t)(NX * NSC));
            for (int i = tid; i < (NX * NSC) / 4; i += 256) ((float4*)sF)[i] = Fg[i];
            if (tid < NSC) sCd[tid] = Cdiag[(bT + t) * NSC + tid];
            if (tid >= 64 && tid < 64 + NSC) sc[tid - 64] = cvec[(bT + t) * NSC + (tid - 64)];
            if (tid >= 128 && tid < 128 + NX) sf[tid - 128] = fvec[(bT + t) * NX + (tid - 128)];
            if (t != T - 1) {
                for (int i = tid; i < NX * NX; i += 256) {
                    const int x1 = i / NX, x2 = i - x1 * NX;
                    sV[i] = 0.5f * (sFV[x1 * NX + x2] + sFV[x2 * NX + x1]);
                }
            }
        }
        __syncthreads();

        // ---- phase B: FV[s][x] = sum_j F[j][s] * V[j][x]; 4x4 tiles ----
        if (tid < 108) {
            const int g = tid / 9;
            const int s0 = g * 4;
            const int x0 = (tid - g * 9) * 4;
            float acc[4][4] = {{0.f}};
            for (int j = 0; j < NX; ++j) {
                const float4 v4 = *(const float4*)&sV[j * NX + x0];
#pragma unroll
                for (int i = 0; i < 4; ++i) {
                    const float fj = sF[j * NSC + s0 + i];
                    acc[i][0] += fj * v4.x; acc[i][1] += fj * v4.y;
                    acc[i][2] += fj * v4.z; acc[i][3] += fj * v4.w;
                }
            }
#pragma unroll
            for (int i = 0; i < 4; ++i)
                *(float4*)&sFV[(s0 + i) * NX + x0] =
                    make_float4(acc[i][0], acc[i][1], acc[i][2], acc[i][3]);
        }
        __syncthreads();

        // ---- phase C: Q = FV * F + diag(Cd) (+REG on u-diag); q vector ----
        if (tid < 144) {
            const int g = tid / 12;
            const int s1 = g * 4;
            const int s2 = (tid - g * 12) * 4;
            float acc[4][4] = {{0.f}};
            for (int x = 0; x < NX; ++x) {
                const float4 fr = *(const float4*)&sF[x * NSC + s2];
#pragma unroll
                for (int i = 0; i < 4; ++i) {
                    const float fv = sFV[(s1 + i) * NX + x];
                    acc[i][0] += fv * fr.x; acc[i][1] += fv * fr.y;
                    acc[i][2] += fv * fr.z; acc[i][3] += fv * fr.w;
                }
            }
#pragma unroll
            for (int i = 0; i < 4; ++i) {
#pragma unroll
                for (int jj = 0; jj < 4; ++jj) {
                    const int r = s1 + i, cl = s2 + jj;
                    float vq = acc[i][jj];
                    if (r == cl) vq += sCd[r] + (r >= NX ? REG_EPS : 0.f);
                    sQ[r * NSC + cl] = vq;
                }
            }
        } else if (tid < 192) {
            const int s = tid - 144;
            float acc = sc[s];
            for (int x = 0; x < NX; ++x) acc += sFV[s * NX + x] * sf[x];
            for (int j = 0; j < NX; ++j) acc += sF[j * NSC + s] * sv[j];
            sq[s] = acc;
        }
        __syncthreads();

        // ---- phase D: solve Quu * Kk = -[Qux | q_u] on wave 0 ----
        // Lane j holds column j of the augmented matrix (12 regs).
        if (tid < 64) {
            float a[NU];
            const int j = tid;
            if (j < NU) {
#pragma unroll
                for (int i = 0; i < NU; ++i) a[i] = sQ[(NX + i) * NSC + NX + j];
            } else if (j < NU + NX) {
                const int x = j - NU;
#pragma unroll
                for (int i = 0; i < NU; ++i) a[i] = sQ[(NX + i) * NSC + x];
            } else if (j == NU + NX) {
#pragma unroll
                for (int i = 0; i < NU; ++i) a[i] = sq[NX + i];
            } else {
#pragma unroll
                for (int i = 0; i < NU; ++i) a[i] = 0.f;
            }
            // forward elimination (SPD: no pivoting)
#pragma unroll
            for (int k = 0; k < NU - 1; ++k) {
                const float piv = __shfl(a[k], k);
                const float invp = 1.0f / piv;
#pragma unroll
                for (int i = k + 1; i < NU; ++i) {
                    const float m = __shfl(a[i], k) * invp;
                    a[i] -= m * a[k];
                }
            }
            // back substitution
            float xs[NU];
#pragma unroll
            for (int k = NU - 1; k >= 0; --k) {
                float s = a[k];
#pragma unroll
                for (int m = k + 1; m < NU; ++m) s -= __shfl(a[k], m) * xs[m];
                xs[k] = s / __shfl(a[k], k);
            }
            // Kk = -solution
            if (j >= NU && j < NU + NX) {
                const int col = j - NU;
#pragma unroll
                for (int k = 0; k < NU; ++k) sK[k * NX + col] = -xs[k];
            } else if (j == NU + NX) {
#pragma unroll
                for (int k = 0; k < NU; ++k) sKv[k] = -xs[k];
            }
        }
        __syncthreads();

        // ---- phase E: unsym Vn -> sFV; vn -> sv; K/kv writeback ----
        if (tid < 81) {
            const int g = tid / 9;
            const int x1 = g * 4;
            const int x2 = (tid - g * 9) * 4;
            float acc[4][4];
#pragma unroll
            for (int i = 0; i < 4; ++i) {
                const float4 qr = *(const float4*)&sQ[(x1 + i) * NSC + x2];
                acc[i][0] = qr.x; acc[i][1] = qr.y; acc[i][2] = qr.z; acc[i][3] = qr.w;
            }
#pragma unroll
            for (int u = 0; u < NU; ++u) {
                const float4 kr = *(const float4*)&sK[u * NX + x2];
#pragma unroll
                for (int i = 0; i < 4; ++i) {
                    const float qx = sQ[(x1 + i) * NSC + NX + u];
                    acc[i][0] += qx * kr.x; acc[i][1] += qx * kr.y;
                    acc[i][2] += qx * kr.z; acc[i][3] += qx * kr.w;
                }
            }
#pragma unroll
            for (int i = 0; i < 4; ++i)
                *(float4*)&sFV[(x1 + i) * NX + x2] =
                    make_float4(acc[i][0], acc[i][1], acc[i][2], acc[i][3]);
        } else if (tid >= 81 && tid < 81 + NX) {
            const int xx = tid - 81;
            float acc = sq[xx];
#pragma unroll
            for (int u = 0; u < NU; ++u) acc += sQ[xx * NSC + NX + u] * sKv[u];
            sv[xx] = acc;
        } else if (tid >= 128) {
            float* Kd = Kg + (bT + t) * (size_t)(NU * NX);
            for (int i = tid - 128; i < NU * NX; i += 128) Kd[i] = sK[i];
            if (tid - 128 < NU) kvg[(bT + t) * NU + (tid - 128)] = sKv[tid - 128];
        }
        __syncthreads();
    }
}

// ---------------------------------------------------------------------------
// Forward rollouts. One block per batch element, 640 threads = 10 waves,
// wave a handles alpha = 0.2^a. MODE 0: costs only -> bestg. MODE 1: store
// all taus to ws, select best, copy to out. MODE 2: replay best alpha only
// (wave 0), write out directly.
// ---------------------------------------------------------------------------
template <int MODE>
__global__ __launch_bounds__(640) void lqr_fwd(
    const float* __restrict__ x0g, const float* __restrict__ Cdiag,
    const float* __restrict__ cvec, const float* __restrict__ Fmat,
    const float* __restrict__ fvec, const float* __restrict__ Kg,
    const float* __restrict__ kvg, float* __restrict__ tausg,
    int* __restrict__ bestg, float* __restrict__ outg, int B, int T)
{
    const int b = blockIdx.x;
    const int tid = threadIdx.x;
    const int wave = tid >> 6;
    const int lane = tid & 63;

    __shared__ float sF[NX * (NSC + 1)];   // padded rows (stride 49)
    __shared__ float sK[NU * (NX + 1)];    // padded rows (stride 37)
    __shared__ float sKv[NU];
    __shared__ float sf[NX];
    __shared__ float sCd[NSC];
    __shared__ float sc[NSC];
    __shared__ float sTau[NLS][NSC];
    __shared__ float sX[NLS][NX];
    __shared__ float sCost[NLS];
    __shared__ int sBest;

    const bool compute = (MODE == 2) ? (wave == 0) : true;

    float alpha = 1.f;
    if (MODE == 2) {
        const int bi0 = bestg[b];
        for (int i = 0; i < bi0; ++i) alpha *= 0.2f;
    } else {
        for (int i = 0; i < wave; ++i) alpha *= 0.2f;
    }

    if (compute && lane < NX) sX[wave][lane] = x0g[(size_t)b * NX + lane];
    float costAcc = 0.f;

    const size_t bT = (size_t)b * (size_t)T;
    for (int t = 0; t < T; ++t) {
        __syncthreads();   // previous-iteration readers done before restage
        {
            const float* Fg = Fmat + (bT + t) * (size_t)(NX * NSC);
            for (int i = tid; i < NX * NSC; i += 640)
                sF[(i / NSC) * (NSC + 1) + (i % NSC)] = Fg[i];
            const float* Kp = Kg + (bT + t) * (size_t)(NU * NX);
            for (int i = tid; i < NU * NX; i += 640)
                sK[(i / NX) * (NX + 1) + (i % NX)] = Kp[i];
            if (tid < NU) sKv[tid] = kvg[(bT + t) * NU + tid];
            if (tid >= 64 && tid < 64 + NX) sf[tid - 64] = fvec[(bT + t) * NX + (tid - 64)];
            if (tid >= 128 && tid < 128 + NSC) sCd[tid - 128] = Cdiag[(bT + t) * NSC + (tid - 128)];
            if (tid >= 192 && tid < 192 + NSC) sc[tid - 192] = cvec[(bT + t) * NSC + (tid - 192)];
        }
        __syncthreads();

        if (compute) {
            // u = K x + alpha * kv   (lanes 0..11)
            if (lane < NU) {
                float uu = alpha * sKv[lane];
#pragma unroll
                for (int x = 0; x < NX; ++x) uu += sK[lane * (NX + 1) + x] * sX[wave][x];
                sTau[wave][NX + lane] = uu;
            }
            if (lane < NX) sTau[wave][lane] = sX[wave][lane];
            __builtin_amdgcn_sched_barrier(0);   // keep LDS writes before reads

            if (MODE != 2 && lane < NSC) {
                const float tv = sTau[wave][lane];
                costAcc += tv * (0.5f * sCd[lane] * tv + sc[lane]);
            }
            if (MODE == 1 && lane < NSC) {
                tausg[(((size_t)wave * B + b) * T + t) * NSC + lane] = sTau[wave][lane];
            }
            if (MODE == 2 && lane < NSC) {
                outg[((size_t)b * T + t) * NSC + lane] = sTau[wave][lane];
            }
            if (lane < NX) {
                float xn = sf[lane];
#pragma unroll
                for (int s = 0; s < NSC; ++s) xn += sF[lane * (NSC + 1) + s] * sTau[wave][s];
                __builtin_amdgcn_sched_barrier(0);
                sX[wave][lane] = xn;
            }
        }
    }

    if (MODE != 2) {
        if (compute) {
            float cs = costAcc;
#pragma unroll
            for (int off = 32; off > 0; off >>= 1) cs += __shfl_down(cs, off);
            if (lane == 0) sCost[wave] = cs;
        }
        __syncthreads();
        if (tid == 0) {
            float bc = sCost[0];
            int bi = 0;
#pragma unroll
            for (int a2 = 1; a2 < NLS; ++a2) {
                if (sCost[a2] < bc) { bc = sCost[a2]; bi = a2; }
            }
            sBest = bi;
            if (MODE == 0) bestg[b] = bi;
        }
        __syncthreads();
        if (MODE == 1) {
            const int bi = sBest;
            const float4* src = (const float4*)(tausg + ((size_t)(bi * B + b)) * T * NSC);
            float4* dst = (float4*)(outg + (size_t)b * T * NSC);
            const int n4 = (T * NSC) / 4;
            for (int i = tid; i < n4; i += 640) dst[i] = src[i];
        }
    }
}

extern "C" void kernel_launch(void* const* d_in, const int* in_sizes, int n_in,
                              void* d_out, int out_size, void* d_ws, size_t ws_size,
                              hipStream_t stream) {
    (void)n_in; (void)out_size;
    const float* x0 = (const float*)d_in[0];
    const float* Cd = (const float*)d_in[1];
    const float* c  = (const float*)d_in[2];
    const float* F  = (const float*)d_in[3];
    const float* f  = (const float*)d_in[4];
    float* out = (float*)d_out;

    const int B = in_sizes[0] / NX;
    const int T = in_sizes[4] / in_sizes[0];

    const size_t nK    = (size_t)B * T * NU * NX;
    const size_t nKv   = (size_t)B * T * NU;
    const size_t nTaus = (size_t)NLS * B * T * NSC;

    float* Kg    = (float*)d_ws;
    float* kvg   = Kg + nK;
    int*   bestg = (int*)(kvg + nKv);
    float* tausg = (float*)(bestg + 256);

    const size_t needA = (nK + nKv + 256 + nTaus) * sizeof(float);
    const bool storeAll = (ws_size >= needA);

    lqr_bwd<<<B, 256, 0, stream>>>(Cd, c, F, f, Kg, kvg, T);
    if (storeAll) {
        lqr_fwd<1><<<B, 640, 0, stream>>>(x0, Cd, c, F, f, Kg, kvg, tausg, bestg, out, B, T);
    } else {
        lqr_fwd<0><<<B, 640, 0, stream>>>(x0, Cd, c, F, f, Kg, kvg, nullptr, bestg, out, B, T);
        lqr_fwd<2><<<B, 640, 0, stream>>>(x0, Cd, c, F, f, Kg, kvg, nullptr, bestg, out, B, T);
    }
}

// Round 2
// 13874.741 us; speedup vs baseline: 1.0242x; 1.0242x over previous
//
#include <hip/hip_runtime.h>
#include <cstdint>
#include <cstddef>

#define NX 36
#define NU 12
#define NSC 48
#define NLS 10
#define REG_EPS 1e-6f

// ---------------------------------------------------------------------------
// Template-unrolled 12x12 solve helpers: EVERY access to the per-lane arrays
// a[] / xs[] uses a template-constant index, so SROA is guaranteed to put
// them in registers (runtime-indexed local arrays go to scratch — that was
// generating ~40 GB of phantom HBM traffic in round 1).
// ---------------------------------------------------------------------------
template <int I> struct LoadA {
    static __device__ __forceinline__ void run(float (&a)[NU], const float* src, int stride) {
        a[I] = src[I * stride];
        LoadA<I + 1>::run(a, src, stride);
    }
};
template <> struct LoadA<NU> {
    static __device__ __forceinline__ void run(float (&)[NU], const float*, int) {}
};

template <int K, int I> struct ElimI {
    static __device__ __forceinline__ void run(float (&a)[NU], float invp) {
        const float m = __shfl(a[I], K) * invp;
        a[I] -= m * a[K];
        ElimI<K, I + 1>::run(a, invp);
    }
};
template <int K> struct ElimI<K, NU> {
    static __device__ __forceinline__ void run(float (&)[NU], float) {}
};

template <int K> struct ElimK {   // forward elimination steps k = 0 .. NU-2
    static __device__ __forceinline__ void run(float (&a)[NU]) {
        const float invp = 1.0f / __shfl(a[K], K);
        ElimI<K, K + 1>::run(a, invp);
        ElimK<K + 1>::run(a);
    }
};
template <> struct ElimK<NU - 1> {
    static __device__ __forceinline__ void run(float (&)[NU]) {}
};

template <int K, int M> struct BackM {
    static __device__ __forceinline__ void run(const float (&a)[NU], const float (&xs)[NU], float& s) {
        s -= __shfl(a[K], M) * xs[M];
        BackM<K, M + 1>::run(a, xs, s);
    }
};
template <int K> struct BackM<K, NU> {
    static __device__ __forceinline__ void run(const float (&)[NU], const float (&)[NU], float&) {}
};

template <int K> struct BackK {   // back substitution k = NU-1 .. 0
    static __device__ __forceinline__ void run(const float (&a)[NU], float (&xs)[NU]) {
        float s = a[K];
        BackM<K, K + 1>::run(a, xs, s);
        xs[K] = s / __shfl(a[K], K);
        BackK<K - 1>::run(a, xs);
    }
};
template <> struct BackK<-1> {
    static __device__ __forceinline__ void run(const float (&)[NU], float (&)[NU]) {}
};

template <int I> struct StoreCol {   // sK[i*NX + col] = -xs[i]
    static __device__ __forceinline__ void run(float* dst, const float (&xs)[NU]) {
        dst[I * NX] = -xs[I];
        StoreCol<I + 1>::run(dst, xs);
    }
};
template <> struct StoreCol<NU> {
    static __device__ __forceinline__ void run(float*, const float (&)[NU]) {}
};

template <int I> struct StoreKv {
    static __device__ __forceinline__ void run(float* dst, const float (&xs)[NU]) {
        dst[I] = -xs[I];
        StoreKv<I + 1>::run(dst, xs);
    }
};
template <> struct StoreKv<NU> {
    static __device__ __forceinline__ void run(float*, const float (&)[NU]) {}
};

// ---------------------------------------------------------------------------
// Backward Riccati recursion. One block per batch element, 256 threads.
// ---------------------------------------------------------------------------
__global__ __launch_bounds__(256, 4) void lqr_bwd(
    const float* __restrict__ Cdiag, const float* __restrict__ cvec,
    const float* __restrict__ Fmat, const float* __restrict__ fvec,
    float* __restrict__ Kg, float* __restrict__ kvg, int T)
{
    const int b = blockIdx.x;
    const int tid = threadIdx.x;

    __shared__ __align__(16) float sV[NX * NX];
    __shared__ float sv[NX];
    __shared__ __align__(16) float sF[NX * NSC];
    __shared__ __align__(16) float sFV[NSC * NX];   // FV; reused for unsym Vn
    __shared__ __align__(16) float sQ[NSC * NSC];
    __shared__ float sq[NSC];
    __shared__ float sCd[NSC];
    __shared__ float sc[NSC];
    __shared__ float sf[NX];
    __shared__ __align__(16) float sK[NU * NX];
    __shared__ float sKv[NU];

    const size_t bT = (size_t)b * (size_t)T;

    for (int i = tid; i < NX * NX; i += 256) sV[i] = 0.f;
    if (tid < NX) sv[tid] = 0.f;

    for (int t = T - 1; t >= 0; --t) {
        // ---- phase A: stage inputs for step t; symmetrize previous Vn ----
        {
            const float4* Fg = (const float4*)(Fmat + (bT + t) * (size_t)(NX * NSC));
            for (int i = tid; i < (NX * NSC) / 4; i += 256) ((float4*)sF)[i] = Fg[i];
            if (tid < NSC) sCd[tid] = Cdiag[(bT + t) * NSC + tid];
            if (tid >= 64 && tid < 64 + NSC) sc[tid - 64] = cvec[(bT + t) * NSC + (tid - 64)];
            if (tid >= 128 && tid < 128 + NX) sf[tid - 128] = fvec[(bT + t) * NX + (tid - 128)];
            if (t != T - 1) {
                for (int i = tid; i < NX * NX; i += 256) {
                    const int x1 = i / NX, x2 = i - x1 * NX;
                    sV[i] = 0.5f * (sFV[x1 * NX + x2] + sFV[x2 * NX + x1]);
                }
            }
        }
        __syncthreads();

        // ---- phase B: FV[s][x] = sum_j F[j][s] * V[j][x]; 4x4 tiles ----
        if (tid < 108) {
            const int g = tid / 9;
            const int s0 = g * 4;
            const int x0 = (tid - g * 9) * 4;
            float acc[4][4] = {{0.f}};
            for (int j = 0; j < NX; ++j) {
                const float4 v4 = *(const float4*)&sV[j * NX + x0];
#pragma unroll
                for (int i = 0; i < 4; ++i) {
                    const float fj = sF[j * NSC + s0 + i];
                    acc[i][0] += fj * v4.x; acc[i][1] += fj * v4.y;
                    acc[i][2] += fj * v4.z; acc[i][3] += fj * v4.w;
                }
            }
#pragma unroll
            for (int i = 0; i < 4; ++i)
                *(float4*)&sFV[(s0 + i) * NX + x0] =
                    make_float4(acc[i][0], acc[i][1], acc[i][2], acc[i][3]);
        }
        __syncthreads();

        // ---- phase C: Q = FV * F + diag(Cd) (+REG on u-diag); q vector ----
        if (tid < 144) {
            const int g = tid / 12;
            const int s1 = g * 4;
            const int s2 = (tid - g * 12) * 4;
            float acc[4][4] = {{0.f}};
            for (int x = 0; x < NX; ++x) {
                const float4 fr = *(const float4*)&sF[x * NSC + s2];
#pragma unroll
                for (int i = 0; i < 4; ++i) {
                    const float fv = sFV[(s1 + i) * NX + x];
                    acc[i][0] += fv * fr.x; acc[i][1] += fv * fr.y;
                    acc[i][2] += fv * fr.z; acc[i][3] += fv * fr.w;
                }
            }
#pragma unroll
            for (int i = 0; i < 4; ++i) {
#pragma unroll
                for (int jj = 0; jj < 4; ++jj) {
                    const int r = s1 + i, cl = s2 + jj;
                    float vq = acc[i][jj];
                    if (r == cl) vq += sCd[r] + (r >= NX ? REG_EPS : 0.f);
                    sQ[r * NSC + cl] = vq;
                }
            }
        } else if (tid < 192) {
            const int s = tid - 144;
            float acc = sc[s];
            for (int x = 0; x < NX; ++x) acc += sFV[s * NX + x] * sf[x];
            for (int j = 0; j < NX; ++j) acc += sF[j * NSC + s] * sv[j];
            sq[s] = acc;
        }
        __syncthreads();

        // ---- phase D: solve Quu * Kk = -[Qux | q_u] on wave 0 ----
        // Lane j holds column j of the augmented matrix (12 regs, template-
        // unrolled: all indices compile-time constants -> guaranteed VGPRs).
        if (tid < 64) {
            const int j = tid;
            const float* src;
            int stride;
            if (j < NU)           { src = &sQ[NX * NSC + NX + j];  stride = NSC; }
            else if (j < NU + NX) { src = &sQ[NX * NSC + (j - NU)]; stride = NSC; }
            else                  { src = &sq[NX];                  stride = 1;   }

            float a[NU];
            LoadA<0>::run(a, src, stride);
            ElimK<0>::run(a);            // SPD: no pivoting
            float xs[NU];
            BackK<NU - 1>::run(a, xs);

            if (j >= NU && j < NU + NX)  StoreCol<0>::run(&sK[j - NU], xs);
            else if (j == NU + NX)       StoreKv<0>::run(sKv, xs);
        }
        __syncthreads();

        // ---- phase E: unsym Vn -> sFV; vn -> sv; K/kv writeback ----
        if (tid < 81) {
            const int g = tid / 9;
            const int x1 = g * 4;
            const int x2 = (tid - g * 9) * 4;
            float acc[4][4];
#pragma unroll
            for (int i = 0; i < 4; ++i) {
                const float4 qr = *(const float4*)&sQ[(x1 + i) * NSC + x2];
                acc[i][0] = qr.x; acc[i][1] = qr.y; acc[i][2] = qr.z; acc[i][3] = qr.w;
            }
#pragma unroll
            for (int u = 0; u < NU; ++u) {
                const float4 kr = *(const float4*)&sK[u * NX + x2];
#pragma unroll
                for (int i = 0; i < 4; ++i) {
                    const float qx = sQ[(x1 + i) * NSC + NX + u];
                    acc[i][0] += qx * kr.x; acc[i][1] += qx * kr.y;
                    acc[i][2] += qx * kr.z; acc[i][3] += qx * kr.w;
                }
            }
#pragma unroll
            for (int i = 0; i < 4; ++i)
                *(float4*)&sFV[(x1 + i) * NX + x2] =
                    make_float4(acc[i][0], acc[i][1], acc[i][2], acc[i][3]);
        } else if (tid >= 81 && tid < 81 + NX) {
            const int xx = tid - 81;
            float acc = sq[xx];
#pragma unroll
            for (int u = 0; u < NU; ++u) acc += sQ[xx * NSC + NX + u] * sKv[u];
            sv[xx] = acc;
        } else if (tid >= 128) {
            float* Kd = Kg + (bT + t) * (size_t)(NU * NX);
            for (int i = tid - 128; i < NU * NX; i += 128) Kd[i] = sK[i];
            if (tid - 128 < NU) kvg[(bT + t) * NU + (tid - 128)] = sKv[tid - 128];
        }
        __syncthreads();
    }
}

// ---------------------------------------------------------------------------
// Forward rollouts. One block per batch element, 640 threads = 10 waves,
// wave a handles alpha = 0.2^a. MODE 0: costs only -> bestg. MODE 1: store
// all taus to ws, select best, copy to out. MODE 2: replay best alpha only
// (wave 0), write out directly.
// ---------------------------------------------------------------------------
template <int MODE>
__global__ __launch_bounds__(640) void lqr_fwd(
    const float* __restrict__ x0g, const float* __restrict__ Cdiag,
    const float* __restrict__ cvec, const float* __restrict__ Fmat,
    const float* __restrict__ fvec, const float* __restrict__ Kg,
    const float* __restrict__ kvg, float* __restrict__ tausg,
    int* __restrict__ bestg, float* __restrict__ outg, int B, int T)
{
    const int b = blockIdx.x;
    const int tid = threadIdx.x;
    const int wave = tid >> 6;
    const int lane = tid & 63;

    __shared__ float sF[NX * (NSC + 1)];   // padded rows (stride 49)
    __shared__ float sK[NU * (NX + 1)];    // padded rows (stride 37)
    __shared__ float sKv[NU];
    __shared__ float sf[NX];
    __shared__ float sCd[NSC];
    __shared__ float sc[NSC];
    __shared__ float sTau[NLS][NSC];
    __shared__ float sX[NLS][NX];
    __shared__ float sCost[NLS];
    __shared__ int sBest;

    const bool compute = (MODE == 2) ? (wave == 0) : true;

    float alpha = 1.f;
    if (MODE == 2) {
        const int bi0 = bestg[b];
        for (int i = 0; i < bi0; ++i) alpha *= 0.2f;
    } else {
        for (int i = 0; i < wave; ++i) alpha *= 0.2f;
    }

    if (compute && lane < NX) sX[wave][lane] = x0g[(size_t)b * NX + lane];
    float costAcc = 0.f;

    const size_t bT = (size_t)b * (size_t)T;
    for (int t = 0; t < T; ++t) {
        __syncthreads();   // previous-iteration readers done before restage
        {
            const float* Fg = Fmat + (bT + t) * (size_t)(NX * NSC);
            for (int i = tid; i < NX * NSC; i += 640)
                sF[(i / NSC) * (NSC + 1) + (i % NSC)] = Fg[i];
            const float* Kp = Kg + (bT + t) * (size_t)(NU * NX);
            for (int i = tid; i < NU * NX; i += 640)
                sK[(i / NX) * (NX + 1) + (i % NX)] = Kp[i];
            if (tid < NU) sKv[tid] = kvg[(bT + t) * NU + tid];
            if (tid >= 64 && tid < 64 + NX) sf[tid - 64] = fvec[(bT + t) * NX + (tid - 64)];
            if (tid >= 128 && tid < 128 + NSC) sCd[tid - 128] = Cdiag[(bT + t) * NSC + (tid - 128)];
            if (tid >= 192 && tid < 192 + NSC) sc[tid - 192] = cvec[(bT + t) * NSC + (tid - 192)];
        }
        __syncthreads();

        if (compute) {
            // u = K x + alpha * kv   (lanes 0..11)
            if (lane < NU) {
                float uu = alpha * sKv[lane];
#pragma unroll
                for (int x = 0; x < NX; ++x) uu += sK[lane * (NX + 1) + x] * sX[wave][x];
                sTau[wave][NX + lane] = uu;
            }
            if (lane < NX) sTau[wave][lane] = sX[wave][lane];
            __builtin_amdgcn_sched_barrier(0);   // keep LDS writes before reads

            if (MODE != 2 && lane < NSC) {
                const float tv = sTau[wave][lane];
                costAcc += tv * (0.5f * sCd[lane] * tv + sc[lane]);
            }
            if (MODE == 1 && lane < NSC) {
                tausg[(((size_t)wave * B + b) * T + t) * NSC + lane] = sTau[wave][lane];
            }
            if (MODE == 2 && lane < NSC) {
                outg[((size_t)b * T + t) * NSC + lane] = sTau[wave][lane];
            }
            if (lane < NX) {
                float xn = sf[lane];
#pragma unroll
                for (int s = 0; s < NSC; ++s) xn += sF[lane * (NSC + 1) + s] * sTau[wave][s];
                __builtin_amdgcn_sched_barrier(0);
                sX[wave][lane] = xn;
            }
        }
    }

    if (MODE != 2) {
        if (compute) {
            float cs = costAcc;
#pragma unroll
            for (int off = 32; off > 0; off >>= 1) cs += __shfl_down(cs, off);
            if (lane == 0) sCost[wave] = cs;
        }
        __syncthreads();
        if (tid == 0) {
            float bc = sCost[0];
            int bi = 0;
#pragma unroll
            for (int a2 = 1; a2 < NLS; ++a2) {
                if (sCost[a2] < bc) { bc = sCost[a2]; bi = a2; }
            }
            sBest = bi;
            if (MODE == 0) bestg[b] = bi;
        }
        __syncthreads();
        if (MODE == 1) {
            const int bi = sBest;
            const float4* src = (const float4*)(tausg + ((size_t)(bi * B + b)) * T * NSC);
            float4* dst = (float4*)(outg + (size_t)b * T * NSC);
            const int n4 = (T * NSC) / 4;
            for (int i = tid; i < n4; i += 640) dst[i] = src[i];
        }
    }
}

extern "C" void kernel_launch(void* const* d_in, const int* in_sizes, int n_in,
                              void* d_out, int out_size, void* d_ws, size_t ws_size,
                              hipStream_t stream) {
    (void)n_in; (void)out_size;
    const float* x0 = (const float*)d_in[0];
    const float* Cd = (const float*)d_in[1];
    const float* c  = (const float*)d_in[2];
    const float* F  = (const float*)d_in[3];
    const float* f  = (const float*)d_in[4];
    float* out = (float*)d_out;

    const int B = in_sizes[0] / NX;
    const int T = in_sizes[4] / in_sizes[0];

    const size_t nK    = (size_t)B * T * NU * NX;
    const size_t nKv   = (size_t)B * T * NU;
    const size_t nTaus = (size_t)NLS * B * T * NSC;

    float* Kg    = (float*)d_ws;
    float* kvg   = Kg + nK;
    int*   bestg = (int*)(kvg + nKv);
    float* tausg = (float*)(bestg + 256);

    const size_t needA = (nK + nKv + 256 + nTaus) * sizeof(float);
    const bool storeAll = (ws_size >= needA);

    lqr_bwd<<<B, 256, 0, stream>>>(Cd, c, F, f, Kg, kvg, T);
    if (storeAll) {
        lqr_fwd<1><<<B, 640, 0, stream>>>(x0, Cd, c, F, f, Kg, kvg, tausg, bestg, out, B, T);
    } else {
        lqr_fwd<0><<<B, 640, 0, stream>>>(x0, Cd, c, F, f, Kg, kvg, nullptr, bestg, out, B, T);
        lqr_fwd<2><<<B, 640, 0, stream>>>(x0, Cd, c, F, f, Kg, kvg, nullptr, bestg, out, B, T);
    }
}

// Round 3
// 4419.955 us; speedup vs baseline: 3.2150x; 3.1391x over previous
//
#include <hip/hip_runtime.h>
#include <cstdint>
#include <cstddef>

#define NX 36
#define NU 12
#define NSC 48
#define NLS 10
#define REG_EPS 1e-6f

// ---------------------------------------------------------------------------
// Template-unrolled 12x12 solve helpers (compile-time indices everywhere).
// ---------------------------------------------------------------------------
template <int I> struct LoadA {
    static __device__ __forceinline__ void run(float (&a)[NU], const float* src, int stride) {
        a[I] = src[I * stride];
        LoadA<I + 1>::run(a, src, stride);
    }
};
template <> struct LoadA<NU> {
    static __device__ __forceinline__ void run(float (&)[NU], const float*, int) {}
};

template <int K, int I> struct ElimI {
    static __device__ __forceinline__ void run(float (&a)[NU], float invp) {
        const float m = __shfl(a[I], K) * invp;
        a[I] -= m * a[K];
        ElimI<K, I + 1>::run(a, invp);
    }
};
template <int K> struct ElimI<K, NU> {
    static __device__ __forceinline__ void run(float (&)[NU], float) {}
};

template <int K> struct ElimK {   // forward elimination steps k = 0 .. NU-2
    static __device__ __forceinline__ void run(float (&a)[NU]) {
        const float invp = 1.0f / __shfl(a[K], K);
        ElimI<K, K + 1>::run(a, invp);
        ElimK<K + 1>::run(a);
    }
};
template <> struct ElimK<NU - 1> {
    static __device__ __forceinline__ void run(float (&)[NU]) {}
};

template <int K, int M> struct BackM {
    static __device__ __forceinline__ void run(const float (&a)[NU], const float (&xs)[NU], float& s) {
        s -= __shfl(a[K], M) * xs[M];
        BackM<K, M + 1>::run(a, xs, s);
    }
};
template <int K> struct BackM<K, NU> {
    static __device__ __forceinline__ void run(const float (&)[NU], const float (&)[NU], float&) {}
};

template <int K> struct BackK {   // back substitution k = NU-1 .. 0
    static __device__ __forceinline__ void run(const float (&a)[NU], float (&xs)[NU]) {
        float s = a[K];
        BackM<K, K + 1>::run(a, xs, s);
        xs[K] = s / __shfl(a[K], K);
        BackK<K - 1>::run(a, xs);
    }
};
template <> struct BackK<-1> {
    static __device__ __forceinline__ void run(const float (&)[NU], float (&)[NU]) {}
};

template <int I> struct StoreCol {   // sK[i*NX + col] = -xs[i]
    static __device__ __forceinline__ void run(float* dst, const float (&xs)[NU]) {
        dst[I * NX] = -xs[I];
        StoreCol<I + 1>::run(dst, xs);
    }
};
template <> struct StoreCol<NU> {
    static __device__ __forceinline__ void run(float*, const float (&)[NU]) {}
};

template <int I> struct StoreKv {
    static __device__ __forceinline__ void run(float* dst, const float (&xs)[NU]) {
        dst[I] = -xs[I];
        StoreKv<I + 1>::run(dst, xs);
    }
};
template <> struct StoreKv<NU> {
    static __device__ __forceinline__ void run(float*, const float (&)[NU]) {}
};

// ---------------------------------------------------------------------------
// Backward Riccati recursion. One block per batch element, 256 threads.
// Round-3 changes: __launch_bounds__(256,2) (256-VGPR budget; the allocator
// was pinning to the 64-reg granule and spilling), and all 4x4 accumulator
// ARRAYS in phases B/C/E replaced with named scalars / float4 registers so
// scratch allocation of the accumulators is structurally impossible.
// ---------------------------------------------------------------------------
__global__ __launch_bounds__(256, 2) void lqr_bwd(
    const float* __restrict__ Cdiag, const float* __restrict__ cvec,
    const float* __restrict__ Fmat, const float* __restrict__ fvec,
    float* __restrict__ Kg, float* __restrict__ kvg, int T)
{
    const int b = blockIdx.x;
    const int tid = threadIdx.x;

    __shared__ __align__(16) float sV[NX * NX];
    __shared__ float sv[NX];
    __shared__ __align__(16) float sF[NX * NSC];
    __shared__ __align__(16) float sFV[NSC * NX];   // FV; reused for unsym Vn
    __shared__ __align__(16) float sQ[NSC * NSC];
    __shared__ float sq[NSC];
    __shared__ float sCd[NSC];
    __shared__ float sc[NSC];
    __shared__ float sf[NX];
    __shared__ __align__(16) float sK[NU * NX];
    __shared__ float sKv[NU];

    const size_t bT = (size_t)b * (size_t)T;

    for (int i = tid; i < NX * NX; i += 256) sV[i] = 0.f;
    if (tid < NX) sv[tid] = 0.f;

    for (int t = T - 1; t >= 0; --t) {
        // ---- phase A: stage inputs for step t; symmetrize previous Vn ----
        {
            const float4* Fg = (const float4*)(Fmat + (bT + t) * (size_t)(NX * NSC));
            for (int i = tid; i < (NX * NSC) / 4; i += 256) ((float4*)sF)[i] = Fg[i];
            if (tid < NSC) sCd[tid] = Cdiag[(bT + t) * NSC + tid];
            if (tid >= 64 && tid < 64 + NSC) sc[tid - 64] = cvec[(bT + t) * NSC + (tid - 64)];
            if (tid >= 128 && tid < 128 + NX) sf[tid - 128] = fvec[(bT + t) * NX + (tid - 128)];
            if (t != T - 1) {
                for (int i = tid; i < NX * NX; i += 256) {
                    const int x1 = i / NX, x2 = i - x1 * NX;
                    sV[i] = 0.5f * (sFV[x1 * NX + x2] + sFV[x2 * NX + x1]);
                }
            }
        }
        __syncthreads();

        // ---- phase B: FV[s][x] = sum_j F[j][s] * V[j][x]; named scalars ----
        if (tid < 108) {
            const int g = tid / 9;
            const int s0 = g * 4;
            const int x0 = (tid - g * 9) * 4;
            float b00 = 0.f, b01 = 0.f, b02 = 0.f, b03 = 0.f;
            float b10 = 0.f, b11 = 0.f, b12 = 0.f, b13 = 0.f;
            float b20 = 0.f, b21 = 0.f, b22 = 0.f, b23 = 0.f;
            float b30 = 0.f, b31 = 0.f, b32 = 0.f, b33 = 0.f;
            for (int j = 0; j < NX; ++j) {
                const float4 v4 = *(const float4*)&sV[j * NX + x0];
                const float f0 = sF[j * NSC + s0 + 0];
                const float f1 = sF[j * NSC + s0 + 1];
                const float f2 = sF[j * NSC + s0 + 2];
                const float f3 = sF[j * NSC + s0 + 3];
                b00 += f0 * v4.x; b01 += f0 * v4.y; b02 += f0 * v4.z; b03 += f0 * v4.w;
                b10 += f1 * v4.x; b11 += f1 * v4.y; b12 += f1 * v4.z; b13 += f1 * v4.w;
                b20 += f2 * v4.x; b21 += f2 * v4.y; b22 += f2 * v4.z; b23 += f2 * v4.w;
                b30 += f3 * v4.x; b31 += f3 * v4.y; b32 += f3 * v4.z; b33 += f3 * v4.w;
            }
            *(float4*)&sFV[(s0 + 0) * NX + x0] = make_float4(b00, b01, b02, b03);
            *(float4*)&sFV[(s0 + 1) * NX + x0] = make_float4(b10, b11, b12, b13);
            *(float4*)&sFV[(s0 + 2) * NX + x0] = make_float4(b20, b21, b22, b23);
            *(float4*)&sFV[(s0 + 3) * NX + x0] = make_float4(b30, b31, b32, b33);
        }
        __syncthreads();

        // ---- phase C: Q = FV * F + diag(Cd) (+REG on u-diag); q vector ----
        if (tid < 144) {
            const int g = tid / 12;
            const int s1 = g * 4;
            const int s2 = (tid - g * 12) * 4;
            float q00 = 0.f, q01 = 0.f, q02 = 0.f, q03 = 0.f;
            float q10 = 0.f, q11 = 0.f, q12 = 0.f, q13 = 0.f;
            float q20 = 0.f, q21 = 0.f, q22 = 0.f, q23 = 0.f;
            float q30 = 0.f, q31 = 0.f, q32 = 0.f, q33 = 0.f;
            for (int x = 0; x < NX; ++x) {
                const float4 fr = *(const float4*)&sF[x * NSC + s2];
                const float e0 = sFV[(s1 + 0) * NX + x];
                const float e1 = sFV[(s1 + 1) * NX + x];
                const float e2 = sFV[(s1 + 2) * NX + x];
                const float e3 = sFV[(s1 + 3) * NX + x];
                q00 += e0 * fr.x; q01 += e0 * fr.y; q02 += e0 * fr.z; q03 += e0 * fr.w;
                q10 += e1 * fr.x; q11 += e1 * fr.y; q12 += e1 * fr.z; q13 += e1 * fr.w;
                q20 += e2 * fr.x; q21 += e2 * fr.y; q22 += e2 * fr.z; q23 += e2 * fr.w;
                q30 += e3 * fr.x; q31 += e3 * fr.y; q32 += e3 * fr.z; q33 += e3 * fr.w;
            }
#define QST(ii, jj, val) do { const int r = s1 + (ii), cl = s2 + (jj); float vq = (val); \
            if (r == cl) vq += sCd[r] + (r >= NX ? REG_EPS : 0.f); sQ[r * NSC + cl] = vq; } while (0)
            QST(0, 0, q00); QST(0, 1, q01); QST(0, 2, q02); QST(0, 3, q03);
            QST(1, 0, q10); QST(1, 1, q11); QST(1, 2, q12); QST(1, 3, q13);
            QST(2, 0, q20); QST(2, 1, q21); QST(2, 2, q22); QST(2, 3, q23);
            QST(3, 0, q30); QST(3, 1, q31); QST(3, 2, q32); QST(3, 3, q33);
#undef QST
        } else if (tid < 192) {
            const int s = tid - 144;
            float acc = sc[s];
            for (int x = 0; x < NX; ++x) acc += sFV[s * NX + x] * sf[x];
            for (int j = 0; j < NX; ++j) acc += sF[j * NSC + s] * sv[j];
            sq[s] = acc;
        }
        __syncthreads();

        // ---- phase D: solve Quu * Kk = -[Qux | q_u] on wave 0 ----
        if (tid < 64) {
            const int j = tid;
            const float* src;
            int stride;
            if (j < NU)           { src = &sQ[NX * NSC + NX + j];   stride = NSC; }
            else if (j < NU + NX) { src = &sQ[NX * NSC + (j - NU)]; stride = NSC; }
            else                  { src = &sq[NX];                  stride = 1;   }

            float a[NU];
            LoadA<0>::run(a, src, stride);
            ElimK<0>::run(a);            // SPD: no pivoting
            float xs[NU];
            BackK<NU - 1>::run(a, xs);

            if (j >= NU && j < NU + NX)  StoreCol<0>::run(&sK[j - NU], xs);
            else if (j == NU + NX)       StoreKv<0>::run(sKv, xs);
        }
        __syncthreads();

        // ---- phase E: unsym Vn -> sFV; vn -> sv; K/kv writeback ----
        if (tid < 81) {
            const int g = tid / 9;
            const int x1 = g * 4;
            const int x2 = (tid - g * 9) * 4;
            float4 r0 = *(const float4*)&sQ[(x1 + 0) * NSC + x2];
            float4 r1 = *(const float4*)&sQ[(x1 + 1) * NSC + x2];
            float4 r2 = *(const float4*)&sQ[(x1 + 2) * NSC + x2];
            float4 r3 = *(const float4*)&sQ[(x1 + 3) * NSC + x2];
            for (int u = 0; u < NU; ++u) {
                const float4 kr = *(const float4*)&sK[u * NX + x2];
                const float p0 = sQ[(x1 + 0) * NSC + NX + u];
                const float p1 = sQ[(x1 + 1) * NSC + NX + u];
                const float p2 = sQ[(x1 + 2) * NSC + NX + u];
                const float p3 = sQ[(x1 + 3) * NSC + NX + u];
                r0.x += p0 * kr.x; r0.y += p0 * kr.y; r0.z += p0 * kr.z; r0.w += p0 * kr.w;
                r1.x += p1 * kr.x; r1.y += p1 * kr.y; r1.z += p1 * kr.z; r1.w += p1 * kr.w;
                r2.x += p2 * kr.x; r2.y += p2 * kr.y; r2.z += p2 * kr.z; r2.w += p2 * kr.w;
                r3.x += p3 * kr.x; r3.y += p3 * kr.y; r3.z += p3 * kr.z; r3.w += p3 * kr.w;
            }
            *(float4*)&sFV[(x1 + 0) * NX + x2] = r0;
            *(float4*)&sFV[(x1 + 1) * NX + x2] = r1;
            *(float4*)&sFV[(x1 + 2) * NX + x2] = r2;
            *(float4*)&sFV[(x1 + 3) * NX + x2] = r3;
        } else if (tid >= 81 && tid < 81 + NX) {
            const int xx = tid - 81;
            float acc = sq[xx];
#pragma unroll
            for (int u = 0; u < NU; ++u) acc += sQ[xx * NSC + NX + u] * sKv[u];
            sv[xx] = acc;
        } else if (tid >= 128) {
            float* Kd = Kg + (bT + t) * (size_t)(NU * NX);
            for (int i = tid - 128; i < NU * NX; i += 128) Kd[i] = sK[i];
            if (tid - 128 < NU) kvg[(bT + t) * NU + (tid - 128)] = sKv[tid - 128];
        }
        __syncthreads();
    }
}

// ---------------------------------------------------------------------------
// Forward rollouts. One block per batch element, 640 threads = 10 waves,
// wave a handles alpha = 0.2^a. MODE 0: costs only -> bestg. MODE 1: store
// all taus to ws, select best, copy to out. MODE 2: replay best alpha only
// (wave 0), write out directly.
// ---------------------------------------------------------------------------
template <int MODE>
__global__ __launch_bounds__(640) void lqr_fwd(
    const float* __restrict__ x0g, const float* __restrict__ Cdiag,
    const float* __restrict__ cvec, const float* __restrict__ Fmat,
    const float* __restrict__ fvec, const float* __restrict__ Kg,
    const float* __restrict__ kvg, float* __restrict__ tausg,
    int* __restrict__ bestg, float* __restrict__ outg, int B, int T)
{
    const int b = blockIdx.x;
    const int tid = threadIdx.x;
    const int wave = tid >> 6;
    const int lane = tid & 63;

    __shared__ float sF[NX * (NSC + 1)];   // padded rows (stride 49)
    __shared__ float sK[NU * (NX + 1)];    // padded rows (stride 37)
    __shared__ float sKv[NU];
    __shared__ float sf[NX];
    __shared__ float sCd[NSC];
    __shared__ float sc[NSC];
    __shared__ float sTau[NLS][NSC];
    __shared__ float sX[NLS][NX];
    __shared__ float sCost[NLS];
    __shared__ int sBest;

    const bool compute = (MODE == 2) ? (wave == 0) : true;

    float alpha = 1.f;
    if (MODE == 2) {
        const int bi0 = bestg[b];
        for (int i = 0; i < bi0; ++i) alpha *= 0.2f;
    } else {
        for (int i = 0; i < wave; ++i) alpha *= 0.2f;
    }

    if (compute && lane < NX) sX[wave][lane] = x0g[(size_t)b * NX + lane];
    float costAcc = 0.f;

    const size_t bT = (size_t)b * (size_t)T;
    for (int t = 0; t < T; ++t) {
        __syncthreads();   // previous-iteration readers done before restage
        {
            const float* Fg = Fmat + (bT + t) * (size_t)(NX * NSC);
            for (int i = tid; i < NX * NSC; i += 640)
                sF[(i / NSC) * (NSC + 1) + (i % NSC)] = Fg[i];
            const float* Kp = Kg + (bT + t) * (size_t)(NU * NX);
            for (int i = tid; i < NU * NX; i += 640)
                sK[(i / NX) * (NX + 1) + (i % NX)] = Kp[i];
            if (tid < NU) sKv[tid] = kvg[(bT + t) * NU + tid];
            if (tid >= 64 && tid < 64 + NX) sf[tid - 64] = fvec[(bT + t) * NX + (tid - 64)];
            if (tid >= 128 && tid < 128 + NSC) sCd[tid - 128] = Cdiag[(bT + t) * NSC + (tid - 128)];
            if (tid >= 192 && tid < 192 + NSC) sc[tid - 192] = cvec[(bT + t) * NSC + (tid - 192)];
        }
        __syncthreads();

        if (compute) {
            // u = K x + alpha * kv   (lanes 0..11)
            if (lane < NU) {
                float uu = alpha * sKv[lane];
#pragma unroll
                for (int x = 0; x < NX; ++x) uu += sK[lane * (NX + 1) + x] * sX[wave][x];
                sTau[wave][NX + lane] = uu;
            }
            if (lane < NX) sTau[wave][lane] = sX[wave][lane];
            __builtin_amdgcn_sched_barrier(0);   // keep LDS writes before reads

            if (MODE != 2 && lane < NSC) {
                const float tv = sTau[wave][lane];
                costAcc += tv * (0.5f * sCd[lane] * tv + sc[lane]);
            }
            if (MODE == 1 && lane < NSC) {
                tausg[(((size_t)wave * B + b) * T + t) * NSC + lane] = sTau[wave][lane];
            }
            if (MODE == 2 && lane < NSC) {
                outg[((size_t)b * T + t) * NSC + lane] = sTau[wave][lane];
            }
            if (lane < NX) {
                float xn = sf[lane];
#pragma unroll
                for (int s = 0; s < NSC; ++s) xn += sF[lane * (NSC + 1) + s] * sTau[wave][s];
                __builtin_amdgcn_sched_barrier(0);
                sX[wave][lane] = xn;
            }
        }
    }

    if (MODE != 2) {
        if (compute) {
            float cs = costAcc;
#pragma unroll
            for (int off = 32; off > 0; off >>= 1) cs += __shfl_down(cs, off);
            if (lane == 0) sCost[wave] = cs;
        }
        __syncthreads();
        if (tid == 0) {
            float bc = sCost[0];
            int bi = 0;
#pragma unroll
            for (int a2 = 1; a2 < NLS; ++a2) {
                if (sCost[a2] < bc) { bc = sCost[a2]; bi = a2; }
            }
            sBest = bi;
            if (MODE == 0) bestg[b] = bi;
        }
        __syncthreads();
        if (MODE == 1) {
            const int bi = sBest;
            const float4* src = (const float4*)(tausg + ((size_t)(bi * B + b)) * T * NSC);
            float4* dst = (float4*)(outg + (size_t)b * T * NSC);
            const int n4 = (T * NSC) / 4;
            for (int i = tid; i < n4; i += 640) dst[i] = src[i];
        }
    }
}

extern "C" void kernel_launch(void* const* d_in, const int* in_sizes, int n_in,
                              void* d_out, int out_size, void* d_ws, size_t ws_size,
                              hipStream_t stream) {
    (void)n_in; (void)out_size;
    const float* x0 = (const float*)d_in[0];
    const float* Cd = (const float*)d_in[1];
    const float* c  = (const float*)d_in[2];
    const float* F  = (const float*)d_in[3];
    const float* f  = (const float*)d_in[4];
    float* out = (float*)d_out;

    const int B = in_sizes[0] / NX;
    const int T = in_sizes[4] / in_sizes[0];

    const size_t nK    = (size_t)B * T * NU * NX;
    const size_t nKv   = (size_t)B * T * NU;
    const size_t nTaus = (size_t)NLS * B * T * NSC;

    float* Kg    = (float*)d_ws;
    float* kvg   = Kg + nK;
    int*   bestg = (int*)(kvg + nKv);
    float* tausg = (float*)(bestg + 256);

    const size_t needA = (nK + nKv + 256 + nTaus) * sizeof(float);
    const bool storeAll = (ws_size >= needA);

    lqr_bwd<<<B, 256, 0, stream>>>(Cd, c, F, f, Kg, kvg, T);
    if (storeAll) {
        lqr_fwd<1><<<B, 640, 0, stream>>>(x0, Cd, c, F, f, Kg, kvg, tausg, bestg, out, B, T);
    } else {
        lqr_fwd<0><<<B, 640, 0, stream>>>(x0, Cd, c, F, f, Kg, kvg, nullptr, bestg, out, B, T);
        lqr_fwd<2><<<B, 640, 0, stream>>>(x0, Cd, c, F, f, Kg, kvg, nullptr, bestg, out, B, T);
    }
}

// Round 4
// 4188.444 us; speedup vs baseline: 3.3927x; 1.0553x over previous
//
#include <hip/hip_runtime.h>
#include <cstdint>
#include <cstddef>

#define NX 36
#define NU 12
#define NSC 48
#define NLS 10
#define REG_EPS 1e-6f

// Wave-synchronous sync: waits all LDS ops of THIS wave (cross-lane handoff),
// leaves global loads (vmcnt) in flight. No s_barrier, no inter-wave skew.
#define WAVE_SYNC() do { asm volatile("s_waitcnt lgkmcnt(0)" ::: "memory"); \
                         __builtin_amdgcn_sched_barrier(0); } while (0)

__device__ __forceinline__ void fma4(float4& a, float s, const float4& b) {
    a.x += s * b.x; a.y += s * b.y; a.z += s * b.z; a.w += s * b.w;
}
__device__ __forceinline__ float dot4(const float4& a, const float4& b) {
    return a.x * b.x + a.y * b.y + a.z * b.z + a.w * b.w;
}

// ---------------------------------------------------------------------------
// Template-unrolled 12x12 solve (compile-time indices -> guaranteed VGPRs).
// ---------------------------------------------------------------------------
template <int I> struct LoadA {
    static __device__ __forceinline__ void run(float (&a)[NU], const float* src, int stride) {
        a[I] = src[I * stride];
        LoadA<I + 1>::run(a, src, stride);
    }
};
template <> struct LoadA<NU> {
    static __device__ __forceinline__ void run(float (&)[NU], const float*, int) {}
};

template <int K, int I> struct ElimI {
    static __device__ __forceinline__ void run(float (&a)[NU], float invp) {
        const float m = __shfl(a[I], K) * invp;
        a[I] -= m * a[K];
        ElimI<K, I + 1>::run(a, invp);
    }
};
template <int K> struct ElimI<K, NU> {
    static __device__ __forceinline__ void run(float (&)[NU], float) {}
};

template <int K> struct ElimK {
    static __device__ __forceinline__ void run(float (&a)[NU]) {
        const float invp = 1.0f / __shfl(a[K], K);
        ElimI<K, K + 1>::run(a, invp);
        ElimK<K + 1>::run(a);
    }
};
template <> struct ElimK<NU - 1> {
    static __device__ __forceinline__ void run(float (&)[NU]) {}
};

template <int K, int M> struct BackM {
    static __device__ __forceinline__ void run(const float (&a)[NU], const float (&xs)[NU], float& s) {
        s -= __shfl(a[K], M) * xs[M];
        BackM<K, M + 1>::run(a, xs, s);
    }
};
template <int K> struct BackM<K, NU> {
    static __device__ __forceinline__ void run(const float (&)[NU], const float (&)[NU], float&) {}
};

template <int K> struct BackK {
    static __device__ __forceinline__ void run(const float (&a)[NU], float (&xs)[NU]) {
        float s = a[K];
        BackM<K, K + 1>::run(a, xs, s);
        xs[K] = s / __shfl(a[K], K);
        BackK<K - 1>::run(a, xs);
    }
};
template <> struct BackK<-1> {
    static __device__ __forceinline__ void run(const float (&)[NU], float (&)[NU]) {}
};

template <int I> struct StoreCol {     // dst[I*NX] = -xs[I]
    static __device__ __forceinline__ void run(float* dst, const float (&xs)[NU]) {
        dst[I * NX] = -xs[I];
        StoreCol<I + 1>::run(dst, xs);
    }
};
template <> struct StoreCol<NU> {
    static __device__ __forceinline__ void run(float*, const float (&)[NU]) {}
};

template <int I> struct StoreKv {      // dst[I] = -xs[I]
    static __device__ __forceinline__ void run(float* dst, const float (&xs)[NU]) {
        dst[I] = -xs[I];
        StoreKv<I + 1>::run(dst, xs);
    }
};
template <> struct StoreKv<NU> {
    static __device__ __forceinline__ void run(float*, const float (&)[NU]) {}
};

// ---------------------------------------------------------------------------
// Backward Riccati: ONE WAVE (64 lanes) per batch element. Zero s_barriers;
// cross-lane handoffs via lgkmcnt(0). F register-staged one step ahead.
//
// Lane mapping for the two big matmuls (B: FV = F^T V, C: Q = FV*F):
//   g = lane>>2 (16 groups), li = lane&3.  Rows s = {g, g+16, g+32},
//   col-chunks (4-wide) cc = {li, li+4, li+8}  ->  3x3 float4 accumulators.
//   x-dim padded to 48 (V cols 36..47 zero; col 36 of V holds v, so
//   FV[s][36] = (F^T v)[s] falls out of phase B for free).
// ---------------------------------------------------------------------------
__global__ __launch_bounds__(64) void lqr_bwd(
    const float* __restrict__ Cdiag, const float* __restrict__ cvec,
    const float* __restrict__ Fmat, const float* __restrict__ fvec,
    float* __restrict__ Kg, float* __restrict__ kvg, int T)
{
    const int b = blockIdx.x;
    const int lane = threadIdx.x;
    const int g = lane >> 2;
    const int li = lane & 3;

    __shared__ __align__(16) float sFd[2][NX * NSC];   // F double buffer
    __shared__ __align__(16) float sV[NX * 48];        // V (col36 = v, rest pad 0)
    __shared__ __align__(16) float sFV[NSC * 40];      // FV (col36 = F^T v)
    __shared__ __align__(16) float sQ[NSC * NSC];
    __shared__ __align__(16) float sK[NU * NX];
    __shared__ float sq[NSC];
    __shared__ float sCd[NSC];
    __shared__ float sc[NSC];
    __shared__ float sf[NX];
    __shared__ float sKv[NU];

    const size_t bT = (size_t)b * (size_t)T;

    // pair-tile mapping for phase E (45 tiles (ti<=tj) of the 9x9 grid)
    int ti = 0, tj = 0;
    if (lane < 45) {
        int rem = lane;
        while (rem >= 9 - ti) { rem -= 9 - ti; ++ti; }
        tj = ti + rem;
    }

    // solve-phase source pointer (lane = column of [Quu | Qux | qu])
    const float* dsrc;
    int dstride;
    if (lane < NU)            { dsrc = &sQ[NX * NSC + NX + lane];      dstride = NSC; }
    else if (lane < NU + NX)  { dsrc = &sQ[NX * NSC + (lane - NU)];    dstride = NSC; }
    else                      { dsrc = &sq[NX];                        dstride = 1;   }

    // ---- prologue: zero sV (incl v=0 col), stage step T-1 ----
    {
        const float4 z4 = make_float4(0.f, 0.f, 0.f, 0.f);
#pragma unroll
        for (int m = 0; m < 7; ++m) {
            const int idx = m * 64 + lane;
            if (idx < (NX * 48) / 4) ((float4*)sV)[idx] = z4;
        }
        const float* Fg = Fmat + (bT + T - 1) * (size_t)(NX * NSC);
#pragma unroll
        for (int m = 0; m < 7; ++m) {
            const int idx = m * 64 + lane;
            if (idx < (NX * NSC) / 4) ((float4*)sFd[0])[idx] = ((const float4*)Fg)[idx];
        }
        if (lane < NSC) { sCd[lane] = Cdiag[(bT + T - 1) * NSC + lane];
                          sc[lane]  = cvec[(bT + T - 1) * NSC + lane]; }
        if (lane < NX)  sf[lane] = fvec[(bT + T - 1) * NX + lane];
    }
    WAVE_SYNC();

    int cur = 0;
    for (int t = T - 1; t >= 0; --t) {
        const float* Fc = &sFd[cur][0];

        // ---- issue next step's loads early (write to LDS after phase D) ----
        float4 stF[7];
        float stCd = 0.f, stC = 0.f, stf = 0.f;
        const bool pre = (t > 0);
        if (pre) {
            const float* Fg = Fmat + (bT + t - 1) * (size_t)(NX * NSC);
#pragma unroll
            for (int m = 0; m < 7; ++m) {
                const int idx = m * 64 + lane;
                if (idx < (NX * NSC) / 4) stF[m] = ((const float4*)Fg)[idx];
            }
            if (lane < NSC) { stCd = Cdiag[(bT + t - 1) * NSC + lane];
                              stC  = cvec[(bT + t - 1) * NSC + lane]; }
            if (lane < NX)  stf = fvec[(bT + t - 1) * NX + lane];
            __builtin_amdgcn_sched_barrier(0);   // keep loads issued here
        }

        // ---- phase B: FV[s][x] = sum_j F[j][s] * V[j][x]  (x padded) ----
        {
            float4 a00 = make_float4(0,0,0,0), a01 = a00, a02 = a00;
            float4 a10 = a00, a11 = a00, a12 = a00;
            float4 a20 = a00, a21 = a00, a22 = a00;
#pragma unroll 4
            for (int j = 0; j < NX; ++j) {
                const float4 v0 = *(const float4*)&sV[j * 48 + 4 * li];
                const float4 v1 = *(const float4*)&sV[j * 48 + 4 * (li + 4)];
                const float4 v2 = *(const float4*)&sV[j * 48 + 4 * (li + 8)];
                const float f0 = Fc[j * NSC + g];
                const float f1 = Fc[j * NSC + g + 16];
                const float f2 = Fc[j * NSC + g + 32];
                fma4(a00, f0, v0); fma4(a01, f0, v1); fma4(a02, f0, v2);
                fma4(a10, f1, v0); fma4(a11, f1, v1); fma4(a12, f1, v2);
                fma4(a20, f2, v0); fma4(a21, f2, v1); fma4(a22, f2, v2);
            }
            // store chunks cc<=9 (cols 0..39 of the 40-wide FV)
            *(float4*)&sFV[g * 40 + 4 * li] = a00;
            *(float4*)&sFV[g * 40 + 4 * (li + 4)] = a01;
            if (li < 2) *(float4*)&sFV[g * 40 + 4 * (li + 8)] = a02;
            *(float4*)&sFV[(g + 16) * 40 + 4 * li] = a10;
            *(float4*)&sFV[(g + 16) * 40 + 4 * (li + 4)] = a11;
            if (li < 2) *(float4*)&sFV[(g + 16) * 40 + 4 * (li + 8)] = a12;
            *(float4*)&sFV[(g + 32) * 40 + 4 * li] = a20;
            *(float4*)&sFV[(g + 32) * 40 + 4 * (li + 4)] = a21;
            if (li < 2) *(float4*)&sFV[(g + 32) * 40 + 4 * (li + 8)] = a22;
        }
        WAVE_SYNC();

        // ---- phase C: Q = FV * F + diag(Cd,+eps) ; then q-vector ----
        {
            float4 q00 = make_float4(0,0,0,0), q01 = q00, q02 = q00;
            float4 q10 = q00, q11 = q00, q12 = q00;
            float4 q20 = q00, q21 = q00, q22 = q00;
#pragma unroll 4
            for (int x = 0; x < NX; ++x) {
                const float4 f0 = *(const float4*)&Fc[x * NSC + 4 * li];
                const float4 f1 = *(const float4*)&Fc[x * NSC + 4 * (li + 4)];
                const float4 f2 = *(const float4*)&Fc[x * NSC + 4 * (li + 8)];
                const float e0 = sFV[g * 40 + x];
                const float e1 = sFV[(g + 16) * 40 + x];
                const float e2 = sFV[(g + 32) * 40 + x];
                fma4(q00, e0, f0); fma4(q01, e0, f1); fma4(q02, e0, f2);
                fma4(q10, e1, f0); fma4(q11, e1, f1); fma4(q12, e1, f2);
                fma4(q20, e2, f0); fma4(q21, e2, f1); fma4(q22, e2, f2);
            }
            // diagonal add, in-accumulator (row g+16k diag lives in slot (k,k))
            if (li == (g >> 2)) {
                const float d0 = sCd[g];
                const float d1 = sCd[g + 16];
                const float d2 = sCd[g + 32] + ((g >= 4) ? REG_EPS : 0.f);
                const int comp = g & 3;
                if      (comp == 0) { q00.x += d0; q11.x += d1; q22.x += d2; }
                else if (comp == 1) { q00.y += d0; q11.y += d1; q22.y += d2; }
                else if (comp == 2) { q00.z += d0; q11.z += d1; q22.z += d2; }
                else                { q00.w += d0; q11.w += d1; q22.w += d2; }
            }
            *(float4*)&sQ[g * NSC + 4 * li] = q00;
            *(float4*)&sQ[g * NSC + 4 * (li + 4)] = q01;
            *(float4*)&sQ[g * NSC + 4 * (li + 8)] = q02;
            *(float4*)&sQ[(g + 16) * NSC + 4 * li] = q10;
            *(float4*)&sQ[(g + 16) * NSC + 4 * (li + 4)] = q11;
            *(float4*)&sQ[(g + 16) * NSC + 4 * (li + 8)] = q12;
            *(float4*)&sQ[(g + 32) * NSC + 4 * li] = q20;
            *(float4*)&sQ[(g + 32) * NSC + 4 * (li + 4)] = q21;
            *(float4*)&sQ[(g + 32) * NSC + 4 * (li + 8)] = q22;
        }
        // q[s] = c[s] + (F^T v)[s] + sum_x FV[s][x] f[x]   (F^T v = FV col 36)
        if (lane < NSC) {
            const int s = lane;
            float acc = sc[s] + sFV[s * 40 + 36];
#pragma unroll
            for (int xc = 0; xc < 9; ++xc) {
                const float4 fv = *(const float4*)&sFV[s * 40 + 4 * xc];
                acc += fv.x * sf[4 * xc] + fv.y * sf[4 * xc + 1]
                     + fv.z * sf[4 * xc + 2] + fv.w * sf[4 * xc + 3];
            }
            sq[s] = acc;
        }
        WAVE_SYNC();

        // ---- phase D: solve Quu * Kk = -[Qux | qu]; K direct to global ----
        if (lane < NU + NX + 1) {
            float a[NU];
            LoadA<0>::run(a, dsrc, dstride);
            ElimK<0>::run(a);                 // SPD: no pivoting
            float xs[NU];
            BackK<NU - 1>::run(a, xs);
            if (lane >= NU && lane < NU + NX) {
                const int col = lane - NU;
                StoreCol<0>::run(&sK[col], xs);
                StoreCol<0>::run(Kg + (bT + t) * (size_t)(NU * NX) + col, xs);
            } else if (lane == NU + NX) {
                StoreKv<0>::run(sKv, xs);
                StoreKv<0>::run(kvg + (bT + t) * NU, xs);
            }
        }
        WAVE_SYNC();

        // ---- write staged next-step inputs (loads have had ~8k cycles) ----
        if (pre) {
            float* nF = &sFd[cur ^ 1][0];
#pragma unroll
            for (int m = 0; m < 7; ++m) {
                const int idx = m * 64 + lane;
                if (idx < (NX * NSC) / 4) ((float4*)nF)[idx] = stF[m];
            }
            if (lane < NSC) { sCd[lane] = stCd; sc[lane] = stC; }
            if (lane < NX)  sf[lane] = stf;
        }

        // ---- phase E: Vn = sym(Qxx + Qxu K) -> sV ; vn -> sV[:,36] ----
        if (lane < 45) {
            float4 wa0 = *(const float4*)&sQ[(4 * ti + 0) * NSC + 4 * tj];
            float4 wa1 = *(const float4*)&sQ[(4 * ti + 1) * NSC + 4 * tj];
            float4 wa2 = *(const float4*)&sQ[(4 * ti + 2) * NSC + 4 * tj];
            float4 wa3 = *(const float4*)&sQ[(4 * ti + 3) * NSC + 4 * tj];
            float4 wb0 = *(const float4*)&sQ[(4 * tj + 0) * NSC + 4 * ti];
            float4 wb1 = *(const float4*)&sQ[(4 * tj + 1) * NSC + 4 * ti];
            float4 wb2 = *(const float4*)&sQ[(4 * tj + 2) * NSC + 4 * ti];
            float4 wb3 = *(const float4*)&sQ[(4 * tj + 3) * NSC + 4 * ti];
#pragma unroll
            for (int u = 0; u < NU; ++u) {
                const float4 ka = *(const float4*)&sK[u * NX + 4 * tj];
                const float4 kb = *(const float4*)&sK[u * NX + 4 * ti];
                fma4(wa0, sQ[(4 * ti + 0) * NSC + NX + u], ka);
                fma4(wa1, sQ[(4 * ti + 1) * NSC + NX + u], ka);
                fma4(wa2, sQ[(4 * ti + 2) * NSC + NX + u], ka);
                fma4(wa3, sQ[(4 * ti + 3) * NSC + NX + u], ka);
                fma4(wb0, sQ[(4 * tj + 0) * NSC + NX + u], kb);
                fma4(wb1, sQ[(4 * tj + 1) * NSC + NX + u], kb);
                fma4(wb2, sQ[(4 * tj + 2) * NSC + NX + u], kb);
                fma4(wb3, sQ[(4 * tj + 3) * NSC + NX + u], kb);
            }
            float4 o0, o1, o2, o3;
            o0.x = 0.5f * (wa0.x + wb0.x); o0.y = 0.5f * (wa0.y + wb1.x);
            o0.z = 0.5f * (wa0.z + wb2.x); o0.w = 0.5f * (wa0.w + wb3.x);
            o1.x = 0.5f * (wa1.x + wb0.y); o1.y = 0.5f * (wa1.y + wb1.y);
            o1.z = 0.5f * (wa1.z + wb2.y); o1.w = 0.5f * (wa1.w + wb3.y);
            o2.x = 0.5f * (wa2.x + wb0.z); o2.y = 0.5f * (wa2.y + wb1.z);
            o2.z = 0.5f * (wa2.z + wb2.z); o2.w = 0.5f * (wa2.w + wb3.z);
            o3.x = 0.5f * (wa3.x + wb0.w); o3.y = 0.5f * (wa3.y + wb1.w);
            o3.z = 0.5f * (wa3.z + wb2.w); o3.w = 0.5f * (wa3.w + wb3.w);
            *(float4*)&sV[(4 * ti + 0) * 48 + 4 * tj] = o0;
            *(float4*)&sV[(4 * ti + 1) * 48 + 4 * tj] = o1;
            *(float4*)&sV[(4 * ti + 2) * 48 + 4 * tj] = o2;
            *(float4*)&sV[(4 * ti + 3) * 48 + 4 * tj] = o3;
            float4 p0, p1, p2, p3;   // transpose for the (tj,ti) block
            p0.x = o0.x; p0.y = o1.x; p0.z = o2.x; p0.w = o3.x;
            p1.x = o0.y; p1.y = o1.y; p1.z = o2.y; p1.w = o3.y;
            p2.x = o0.z; p2.y = o1.z; p2.z = o2.z; p2.w = o3.z;
            p3.x = o0.w; p3.y = o1.w; p3.z = o2.w; p3.w = o3.w;
            *(float4*)&sV[(4 * tj + 0) * 48 + 4 * ti] = p0;
            *(float4*)&sV[(4 * tj + 1) * 48 + 4 * ti] = p1;
            *(float4*)&sV[(4 * tj + 2) * 48 + 4 * ti] = p2;
            *(float4*)&sV[(4 * tj + 3) * 48 + 4 * ti] = p3;
        }
        if (lane >= 45) {
            const int x1 = lane - 45;
#pragma unroll
            for (int h = 0; h < 2; ++h) {
                const int xx = x1 + 19 * h;
                if (xx < NX) {
                    float acc = sq[xx];
#pragma unroll
                    for (int u = 0; u < NU; ++u) acc += sQ[xx * NSC + NX + u] * sKv[u];
                    sV[xx * 48 + 36] = acc;    // v lives in col 36 of V
                }
            }
        }
        WAVE_SYNC();
        cur ^= 1;
    }
}

// ---------------------------------------------------------------------------
// Forward rollouts: ONE WAVE per batch element, all 10 alphas in-wave
// (6 lanes per alpha). MODE 0: costs -> bestg. MODE 2: replay best alpha,
// write out. Zero barriers; F/K register-staged one step ahead.
// ---------------------------------------------------------------------------
template <int MODE>
__global__ __launch_bounds__(64) void lqr_fwd(
    const float* __restrict__ x0g, const float* __restrict__ Cdiag,
    const float* __restrict__ cvec, const float* __restrict__ Fmat,
    const float* __restrict__ fvec, const float* __restrict__ Kg,
    const float* __restrict__ kvg, int* __restrict__ bestg,
    float* __restrict__ outg, int B, int T)
{
    const int b = blockIdx.x;
    const int lane = threadIdx.x;
    const int a = lane / 6;
    const int r = lane - a * 6;
    const int aa = (lane < 60) ? a : 0;

    __shared__ __align__(16) float sFf[NX * NSC];
    __shared__ __align__(16) float sKf[NU * NX];
    __shared__ __align__(16) float sTau[NLS][52];
    __shared__ float sKv[NU];
    __shared__ float sCd[NSC];
    __shared__ float sc[NSC];
    __shared__ float sff[NX];
    __shared__ float sCost[64];

    float alpha = 1.f;
    if (MODE == 2) {
        const int bi = bestg[b];
        for (int i = 0; i < bi; ++i) alpha *= 0.2f;
    } else {
        for (int i = 0; i < a && i < NLS; ++i) alpha *= 0.2f;
    }

    float x[6];
#pragma unroll
    for (int m = 0; m < 6; ++m) x[m] = x0g[(size_t)b * NX + r + 6 * m];

    const size_t bT = (size_t)b * (size_t)T;

    // prologue: stage t = 0
    {
        const float* Fg = Fmat + bT * (size_t)(NX * NSC);
#pragma unroll
        for (int m = 0; m < 7; ++m) {
            const int idx = m * 64 + lane;
            if (idx < (NX * NSC) / 4) ((float4*)sFf)[idx] = ((const float4*)Fg)[idx];
        }
        const float* Kp = Kg + bT * (size_t)(NU * NX);
#pragma unroll
        for (int m = 0; m < 2; ++m) {
            const int idx = m * 64 + lane;
            if (idx < (NU * NX) / 4) ((float4*)sKf)[idx] = ((const float4*)Kp)[idx];
        }
        if (lane < NU) sKv[lane] = kvg[bT * NU + lane];
        if (MODE == 0 && lane < NSC) { sCd[lane] = Cdiag[bT * NSC + lane];
                                       sc[lane]  = cvec[bT * NSC + lane]; }
        if (lane < NX) sff[lane] = fvec[bT * NX + lane];
    }
    WAVE_SYNC();

    float costAcc = 0.f;
    for (int t = 0; t < T; ++t) {
        // issue next step's loads
        float4 stF[7]; float4 stK[2];
        float stKv = 0.f, stCd = 0.f, stC = 0.f, stf = 0.f;
        const bool pre = (t + 1 < T);
        if (pre) {
            const float* Fg = Fmat + (bT + t + 1) * (size_t)(NX * NSC);
#pragma unroll
            for (int m = 0; m < 7; ++m) {
                const int idx = m * 64 + lane;
                if (idx < (NX * NSC) / 4) stF[m] = ((const float4*)Fg)[idx];
            }
            const float* Kp = Kg + (bT + t + 1) * (size_t)(NU * NX);
#pragma unroll
            for (int m = 0; m < 2; ++m) {
                const int idx = m * 64 + lane;
                if (idx < (NU * NX) / 4) stK[m] = ((const float4*)Kp)[idx];
            }
            if (lane < NU) stKv = kvg[(bT + t + 1) * NU + lane];
            if (MODE == 0 && lane < NSC) { stCd = Cdiag[(bT + t + 1) * NSC + lane];
                                           stC  = cvec[(bT + t + 1) * NSC + lane]; }
            if (lane < NX) stf = fvec[(bT + t + 1) * NX + lane];
            __builtin_amdgcn_sched_barrier(0);
        }

        // P1: publish x into tau; x-part cost
        if (lane < 60) {
#pragma unroll
            for (int m = 0; m < 6; ++m) sTau[aa][r + 6 * m] = x[m];
            if (MODE == 0) {
#pragma unroll
                for (int m = 0; m < 6; ++m) {
                    const int s = r + 6 * m;
                    costAcc += x[m] * (0.5f * sCd[s] * x[m] + sc[s]);
                }
            }
        }
        WAVE_SYNC();

        // P2: u = K x + alpha kv  (2 rows per lane); u-part cost
        float4 tc[9];
#pragma unroll
        for (int c = 0; c < 9; ++c) tc[c] = *(const float4*)&sTau[aa][4 * c];
#pragma unroll
        for (int ii = 0; ii < 2; ++ii) {
            const int i = r + 6 * ii;
            float acc = alpha * sKv[i];
#pragma unroll
            for (int c = 0; c < 9; ++c)
                acc += dot4(*(const float4*)&sKf[i * NX + 4 * c], tc[c]);
            if (lane < 60) {
                sTau[aa][NX + i] = acc;
                if (MODE == 0) costAcc += acc * (0.5f * sCd[NX + i] * acc + sc[NX + i]);
            }
        }
        WAVE_SYNC();

        if (MODE == 2 && lane < NSC)
            outg[((size_t)b * T + t) * NSC + lane] = sTau[0][lane];

        // P3: x' = F tau + f  (6 rows per lane)
        float4 tu[3];
#pragma unroll
        for (int c = 0; c < 3; ++c) tu[c] = *(const float4*)&sTau[aa][NX + 4 * c];
#pragma unroll
        for (int m = 0; m < 6; ++m) {
            const int row = r + 6 * m;
            float acc = sff[row];
#pragma unroll
            for (int c = 0; c < 9; ++c)
                acc += dot4(*(const float4*)&sFf[row * NSC + 4 * c], tc[c]);
#pragma unroll
            for (int c = 0; c < 3; ++c)
                acc += dot4(*(const float4*)&sFf[row * NSC + NX + 4 * c], tu[c]);
            x[m] = acc;
        }
        WAVE_SYNC();   // P3 LDS reads complete before staging overwrite

        if (pre) {
#pragma unroll
            for (int m = 0; m < 7; ++m) {
                const int idx = m * 64 + lane;
                if (idx < (NX * NSC) / 4) ((float4*)sFf)[idx] = stF[m];
            }
#pragma unroll
            for (int m = 0; m < 2; ++m) {
                const int idx = m * 64 + lane;
                if (idx < (NU * NX) / 4) ((float4*)sKf)[idx] = stK[m];
            }
            if (lane < NU) sKv[lane] = stKv;
            if (MODE == 0 && lane < NSC) { sCd[lane] = stCd; sc[lane] = stC; }
            if (lane < NX) sff[lane] = stf;
        }
        WAVE_SYNC();
    }

    if (MODE == 0) {
        sCost[lane] = costAcc;
        WAVE_SYNC();
        if (lane < NLS) {
            float s = 0.f;
#pragma unroll
            for (int rr = 0; rr < 6; ++rr) s += sCost[lane * 6 + rr];
            sCost[lane] = s;   // all reads precede writes in the wave's stream
        }
        WAVE_SYNC();
        if (lane == 0) {
            float bc = sCost[0]; int bi = 0;
#pragma unroll
            for (int a2 = 1; a2 < NLS; ++a2)
                if (sCost[a2] < bc) { bc = sCost[a2]; bi = a2; }
            bestg[b] = bi;
        }
    }
}

extern "C" void kernel_launch(void* const* d_in, const int* in_sizes, int n_in,
                              void* d_out, int out_size, void* d_ws, size_t ws_size,
                              hipStream_t stream) {
    (void)n_in; (void)out_size; (void)ws_size;
    const float* x0 = (const float*)d_in[0];
    const float* Cd = (const float*)d_in[1];
    const float* c  = (const float*)d_in[2];
    const float* F  = (const float*)d_in[3];
    const float* f  = (const float*)d_in[4];
    float* out = (float*)d_out;

    const int B = in_sizes[0] / NX;
    const int T = in_sizes[4] / in_sizes[0];

    const size_t nK  = (size_t)B * T * NU * NX;
    const size_t nKv = (size_t)B * T * NU;

    float* Kg    = (float*)d_ws;
    float* kvg   = Kg + nK;
    int*   bestg = (int*)(kvg + nKv);

    lqr_bwd<<<B, 64, 0, stream>>>(Cd, c, F, f, Kg, kvg, T);
    lqr_fwd<0><<<B, 64, 0, stream>>>(x0, Cd, c, F, f, Kg, kvg, bestg, out, B, T);
    lqr_fwd<2><<<B, 64, 0, stream>>>(x0, Cd, c, F, f, Kg, kvg, bestg, out, B, T);
}